// Round 9
// baseline (90.900 us; speedup 1.0000x reference)
//
#include <hip/hip_runtime.h>
#include <hip/hip_bf16.h>

#define EMB 16
#define HID 64
#define NE  8
#define TPG 64   // tokens per wave-group
#define NWAVE 8  // waves per block

typedef float  f32x4 __attribute__((ext_vector_type(4)));
typedef double f64x4 __attribute__((ext_vector_type(4)));
typedef short  s16x4 __attribute__((ext_vector_type(4)));

// fp32 -> bf16 via the standard HIP cast (RNE). Per learn_hip m240 the compiler
// fuses adjacent converts into v_cvt_pk_bf16_f32 on its own; round-8's hand
// inline-asm cvt_pk produced NaN (suspected upper-half semantics) — reverted.
__device__ __forceinline__ short f2bf(float f) {
    union { __hip_bfloat16 h; short s; } u;
    u.h = __float2bfloat16(f);
    return u.s;
}
__device__ __forceinline__ s16x4 pack_bf16x4(float a, float b, float c, float d) {
    s16x4 r;
    r[0] = f2bf(a); r[1] = f2bf(b); r[2] = f2bf(c); r[3] = f2bf(d);
    return r;
}

__device__ __forceinline__ f32x4 vfmaf(float s, f32x4 a, f32x4 c) {
    f32x4 r;
    r[0] = fmaf(s, a[0], c[0]); r[1] = fmaf(s, a[1], c[1]);
    r[2] = fmaf(s, a[2], c[2]); r[3] = fmaf(s, a[3], c[3]);
    return r;
}
__device__ __forceinline__ f64x4 vfmad(double s, f32x4 a, f64x4 c) {
    f64x4 r;
    r[0] = fma(s, (double)a[0], c[0]); r[1] = fma(s, (double)a[1], c[1]);
    r[2] = fma(s, (double)a[2], c[2]); r[3] = fma(s, (double)a[3], c[3]);
    return r;
}

// ============================================================================
// Single fused kernel. Router is array-free (round-7 proved it spill-clean).
// Gates pass through a wave-private LDS slab; x is read once; no workspace.
// ============================================================================
__global__ __launch_bounds__(512, 2)
void moe_onepass(const float* __restrict__ x, const float* __restrict__ Wr,
                 const float* __restrict__ br, const float* __restrict__ W1,
                 const float* __restrict__ b1, const float* __restrict__ W2,
                 const float* __restrict__ b2, float* __restrict__ out,
                 int n_tokens)
{
    __shared__ __align__(16) s16x4 w1lds[NE * 4 * 64];       // 16 KB: [e][n][lane]
    __shared__ __align__(16) s16x4 w2lds[NE * 4 * 64];       // 16 KB: [e][q][lane]
    __shared__ __align__(16) float b1_lds[NE * HID];         // 2 KB
    __shared__ __align__(16) float b2_lds[NE * EMB];         // 512 B
    __shared__ __align__(16) float wr_lds[EMB * NE];         // 512 B
    __shared__ __align__(16) float br_lds[NE];
    __shared__ __align__(16) float wt_lds[NWAVE * NE * TPG]; // 16 KB: [wave][e][tok]

    const int tid = threadIdx.x;

    // ---- per-block preamble: weights fp32->bf16 in per-lane fragment order ----
    // w1lds[(e*4+n)*64 + lane(cg,col)][j] = W1[e][4cg+j][16n+col]   (G1 A-frag, swapped)
    // w2lds[(e*4+q)*64 + lane(cg,col)][j] = W2[e][16q+4cg+j][col]   (G2 A-frag, swapped)
    for (int s = tid; s < NE * 4 * 64; s += 512) {
        const int e = s >> 8, nq = (s >> 6) & 3, l = s & 63;
        const int cc = l & 15, gg = (l >> 4) & 3;
        const float* w1p = W1 + (e * EMB + 4 * gg) * HID + 16 * nq + cc;
        const float* w2p = W2 + (e * HID + 16 * nq + 4 * gg) * EMB + cc;
        w1lds[s] = pack_bf16x4(w1p[0], w1p[HID], w1p[2 * HID], w1p[3 * HID]);
        w2lds[s] = pack_bf16x4(w2p[0], w2p[EMB], w2p[2 * EMB], w2p[3 * EMB]);
    }
    for (int i = tid; i < NE * HID; i += 512) b1_lds[i] = b1[i];
    if (tid < NE * EMB) b2_lds[tid] = b2[tid];
    if (tid < EMB * NE) wr_lds[tid] = Wr[tid];
    if (tid < NE) br_lds[tid] = br[tid];
    __syncthreads();

    const int lane = tid & 63;
    const int wid  = tid >> 6;
    const int col  = lane & 15;
    const int cg   = lane >> 4;
    float* wtw = wt_lds + wid * (NE * TPG);   // wave-private gate slab

    const int n_groups = n_tokens / TPG;
    for (int g = blockIdx.x * NWAVE + wid; g < n_groups; g += gridDim.x * NWAVE) {
        const int tok0 = g * TPG;

        // ============ router: lane owns token tok0+lane; ZERO arrays ============
        {
            const f32x4* xp = (const f32x4*)(x + (size_t)(tok0 + lane) * EMB);
            const f32x4 x0 = xp[0], x1 = xp[1], x2 = xp[2], x3 = xp[3];

            f32x4 lgA = *(const f32x4*)(br_lds + 0);
            f32x4 lgB = *(const f32x4*)(br_lds + 4);
#define RSTEP(K, XV) do { const float xv_ = (XV); \
        lgA = vfmaf(xv_, *(const f32x4*)(wr_lds + (K) * NE),     lgA); \
        lgB = vfmaf(xv_, *(const f32x4*)(wr_lds + (K) * NE + 4), lgB); } while (0)
            RSTEP(0,  x0[0]); RSTEP(1,  x0[1]); RSTEP(2,  x0[2]); RSTEP(3,  x0[3]);
            RSTEP(4,  x1[0]); RSTEP(5,  x1[1]); RSTEP(6,  x1[2]); RSTEP(7,  x1[3]);
            RSTEP(8,  x2[0]); RSTEP(9,  x2[1]); RSTEP(10, x2[2]); RSTEP(11, x2[3]);
            RSTEP(12, x3[0]); RSTEP(13, x3[1]); RSTEP(14, x3[2]); RSTEP(15, x3[3]);
#undef RSTEP

            float m1 = -1e30f, m2 = -1e30f, m3 = -1e30f;
#define MSCAN(V) do { const float v_ = (V); \
        const float hi_ = fmaxf(m1, v_), lo_ = fminf(m1, v_); \
        const float hi2_ = fmaxf(m2, lo_), lo2_ = fminf(m2, lo_); \
        m1 = hi_; m2 = hi2_; m3 = fmaxf(m3, lo2_); } while (0)
            MSCAN(lgA[0]); MSCAN(lgA[1]); MSCAN(lgA[2]); MSCAN(lgA[3]);
            MSCAN(lgB[0]); MSCAN(lgB[1]); MSCAN(lgB[2]); MSCAN(lgB[3]);
#undef MSCAN

            int sm = 0;
            sm |= (lgA[0] >= m2) << 0; sm |= (lgA[1] >= m2) << 1;
            sm |= (lgA[2] >= m2) << 2; sm |= (lgA[3] >= m2) << 3;
            sm |= (lgB[0] >= m2) << 4; sm |= (lgB[1] >= m2) << 5;
            sm |= (lgB[2] >= m2) << 6; sm |= (lgB[3] >= m2) << 7;

            // near-tie rescue: wave-uniform fp64 recompute (~2.5% of waves)
            if (__any(m2 - m3 < 1e-4f)) {
                f64x4 dA, dB;
                dA[0] = (double)br_lds[0]; dA[1] = (double)br_lds[1];
                dA[2] = (double)br_lds[2]; dA[3] = (double)br_lds[3];
                dB[0] = (double)br_lds[4]; dB[1] = (double)br_lds[5];
                dB[2] = (double)br_lds[6]; dB[3] = (double)br_lds[7];
#define DSTEP(K, XV) do { const double xv_ = (double)(XV); \
        dA = vfmad(xv_, *(const f32x4*)(wr_lds + (K) * NE),     dA); \
        dB = vfmad(xv_, *(const f32x4*)(wr_lds + (K) * NE + 4), dB); } while (0)
                DSTEP(0,  x0[0]); DSTEP(1,  x0[1]); DSTEP(2,  x0[2]); DSTEP(3,  x0[3]);
                DSTEP(4,  x1[0]); DSTEP(5,  x1[1]); DSTEP(6,  x1[2]); DSTEP(7,  x1[3]);
                DSTEP(8,  x2[0]); DSTEP(9,  x2[1]); DSTEP(10, x2[2]); DSTEP(11, x2[3]);
                DSTEP(12, x3[0]); DSTEP(13, x3[1]); DSTEP(14, x3[2]); DSTEP(15, x3[3]);
#undef DSTEP
                double M1 = -1e300, M2 = -1e300;
#define DSCAN(V) do { const double v_ = (V); \
        const double hi_ = fmax(M1, v_); M2 = fmax(M2, fmin(M1, v_)); M1 = hi_; } while (0)
                DSCAN(dA[0]); DSCAN(dA[1]); DSCAN(dA[2]); DSCAN(dA[3]);
                DSCAN(dB[0]); DSCAN(dB[1]); DSCAN(dB[2]); DSCAN(dB[3]);
#undef DSCAN
                sm = 0;
                sm |= (dA[0] >= M2) << 0; sm |= (dA[1] >= M2) << 1;
                sm |= (dA[2] >= M2) << 2; sm |= (dA[3] >= M2) << 3;
                sm |= (dB[0] >= M2) << 4; sm |= (dB[1] >= M2) << 5;
                sm |= (dB[2] >= M2) << 6; sm |= (dB[3] >= M2) << 7;
            }

            const float e0 = __expf(lgA[0] - m1), e1 = __expf(lgA[1] - m1);
            const float e2 = __expf(lgA[2] - m1), e3 = __expf(lgA[3] - m1);
            const float e4 = __expf(lgB[0] - m1), e5 = __expf(lgB[1] - m1);
            const float e6 = __expf(lgB[2] - m1), e7 = __expf(lgB[3] - m1);
            const float inv = 1.0f / (e0 + e1 + e2 + e3 + e4 + e5 + e6 + e7);
            wtw[0 * TPG + lane] = (sm & 1)   ? e0 * inv : 0.f;
            wtw[1 * TPG + lane] = (sm & 2)   ? e1 * inv : 0.f;
            wtw[2 * TPG + lane] = (sm & 4)   ? e2 * inv : 0.f;
            wtw[3 * TPG + lane] = (sm & 8)   ? e3 * inv : 0.f;
            wtw[4 * TPG + lane] = (sm & 16)  ? e4 * inv : 0.f;
            wtw[5 * TPG + lane] = (sm & 32)  ? e5 * inv : 0.f;
            wtw[6 * TPG + lane] = (sm & 64)  ? e6 * inv : 0.f;
            wtw[7 * TPG + lane] = (sm & 128) ? e7 * inv : 0.f;
            // wave-private write->read; compiler orders via lgkmcnt, no barrier
        }

        // ============ MoE: one 16-token tile at a time, minimal live set ============
#pragma unroll 1
        for (int T = 0; T < 4; ++T) {
            const int tok = tok0 + 16 * T + col;
            // G1 B-frag: B[k=4cg+j][tok=col] = x[tok][4cg+j]
            const f32x4 xv = *(const f32x4*)(x + (size_t)tok * EMB + 4 * cg);
            const s16x4 xb = pack_bf16x4(xv[0], xv[1], xv[2], xv[3]);

            f32x4 oacc = {0.f, 0.f, 0.f, 0.f};
#pragma unroll 1
            for (int e = 0; e < NE; ++e) {
                const float wv = wtw[e * TPG + 16 * T + col];
                // bias term: oacc += w_e * b2[e][4cg+r] (bypasses relu-weighting)
                const f32x4 b2c = *(const f32x4*)(b2_lds + e * EMB + 4 * cg);
                oacc = vfmaf(wv, b2c, oacc);
                // G1: h^T tile n (lane: h[tok=col][hid=16n+4cg+r]), C-in = b1
                f32x4 h[4];
#pragma unroll
                for (int n = 0; n < 4; ++n) {
                    const s16x4 a1  = w1lds[(e * 4 + n) * 64 + lane];
                    const f32x4 b1c = *(const f32x4*)(b1_lds + e * HID + 16 * n + 4 * cg);
                    h[n] = __builtin_amdgcn_mfma_f32_16x16x16bf16_1k(a1, xb, b1c, 0, 0, 0);
                }
                // G2 swapped: eoT[emb][tok]; A = W2^T frag, B = w*relu(h); C chains q AND e
#pragma unroll
                for (int q = 0; q < 4; ++q) {
                    const s16x4 a2 = w2lds[(e * 4 + q) * 64 + lane];
                    const s16x4 b  = pack_bf16x4(fmaxf(h[q][0], 0.f) * wv,
                                                 fmaxf(h[q][1], 0.f) * wv,
                                                 fmaxf(h[q][2], 0.f) * wv,
                                                 fmaxf(h[q][3], 0.f) * wv);
                    oacc = __builtin_amdgcn_mfma_f32_16x16x16bf16_1k(a2, b, oacc, 0, 0, 0);
                }
            }

            // lane owns token 16T+col, emb 4cg..4cg+3 -> wave stores 1 KB contiguous
            __builtin_nontemporal_store(oacc, (f32x4*)(out + (size_t)tok * EMB + 4 * cg));
        }
    }
}

extern "C" void kernel_launch(void* const* d_in, const int* in_sizes, int n_in,
                              void* d_out, int out_size, void* d_ws, size_t ws_size,
                              hipStream_t stream) {
    const float* x  = (const float*)d_in[0];
    const float* Wr = (const float*)d_in[1];
    const float* br = (const float*)d_in[2];
    const float* W1 = (const float*)d_in[3];
    const float* b1 = (const float*)d_in[4];
    const float* W2 = (const float*)d_in[5];
    const float* b2 = (const float*)d_in[6];
    float* out = (float*)d_out;

    const int n_tokens = in_sizes[0] / EMB;   // 262144
    // 512 blocks x 8 waves = 4096 waves = one 64-token group per wave.
    hipLaunchKernelGGL(moe_onepass, dim3(512), dim3(512), 0, stream,
                       x, Wr, br, W1, b1, W2, b2, out, n_tokens);
}

// Round 10
// 39.428 us; speedup vs baseline: 2.3054x; 2.3054x over previous
//
#include <hip/hip_runtime.h>
#include <hip/hip_bf16.h>

#define EMB 16
#define HID 64
#define NE  8
#define TPG 64   // tokens per wave-group

typedef float  f32x4 __attribute__((ext_vector_type(4)));
typedef double f64x4 __attribute__((ext_vector_type(4)));
typedef short  s16x4 __attribute__((ext_vector_type(4)));

// fp32 -> bf16 via the standard HIP cast (RNE).
__device__ __forceinline__ short f2bf(float f) {
    union { __hip_bfloat16 h; short s; } u;
    u.h = __float2bfloat16(f);
    return u.s;
}
__device__ __forceinline__ s16x4 pack_bf16x4(float a, float b, float c, float d) {
    s16x4 r;
    r[0] = f2bf(a); r[1] = f2bf(b); r[2] = f2bf(c); r[3] = f2bf(d);
    return r;
}

__device__ __forceinline__ f32x4 vfmaf(float s, f32x4 a, f32x4 c) {
    f32x4 r;
    r[0] = fmaf(s, a[0], c[0]); r[1] = fmaf(s, a[1], c[1]);
    r[2] = fmaf(s, a[2], c[2]); r[3] = fmaf(s, a[3], c[3]);
    return r;
}
__device__ __forceinline__ f64x4 vfmad(double s, f32x4 a, f64x4 c) {
    f64x4 r;
    r[0] = fma(s, (double)a[0], c[0]); r[1] = fma(s, (double)a[1], c[1]);
    r[2] = fma(s, (double)a[2], c[2]); r[3] = fma(s, (double)a[3], c[3]);
    return r;
}

// ============================================================================
// Kernel 1: router (byte-identical to round 7 — proven spill-clean, ~8 us).
// One thread per token, ZERO arrays, wave-uniform fp64 rescue.
// ============================================================================
__global__ __launch_bounds__(256, 2)
void router_k(const float* __restrict__ x, const float* __restrict__ Wr,
              const float* __restrict__ br, float* __restrict__ gates,
              int n_tokens)
{
    __shared__ float wr_lds[EMB * NE];
    __shared__ float br_lds[NE];
    const int tid = threadIdx.x;
    if (tid < EMB * NE) wr_lds[tid] = Wr[tid];
    if (tid < NE) br_lds[tid] = br[tid];
    __syncthreads();

    const int t = blockIdx.x * 256 + tid;
    if (t >= n_tokens) return;

    const f32x4* xp = (const f32x4*)(x + (size_t)t * EMB);
    const f32x4 x0 = xp[0], x1 = xp[1], x2 = xp[2], x3 = xp[3];

    f32x4 lgA = *(const f32x4*)(br_lds + 0);
    f32x4 lgB = *(const f32x4*)(br_lds + 4);
#define RSTEP(K, XV) do { const float xv_ = (XV); \
        lgA = vfmaf(xv_, *(const f32x4*)(wr_lds + (K) * NE),     lgA); \
        lgB = vfmaf(xv_, *(const f32x4*)(wr_lds + (K) * NE + 4), lgB); } while (0)
    RSTEP(0,  x0[0]); RSTEP(1,  x0[1]); RSTEP(2,  x0[2]); RSTEP(3,  x0[3]);
    RSTEP(4,  x1[0]); RSTEP(5,  x1[1]); RSTEP(6,  x1[2]); RSTEP(7,  x1[3]);
    RSTEP(8,  x2[0]); RSTEP(9,  x2[1]); RSTEP(10, x2[2]); RSTEP(11, x2[3]);
    RSTEP(12, x3[0]); RSTEP(13, x3[1]); RSTEP(14, x3[2]); RSTEP(15, x3[3]);
#undef RSTEP

    float m1 = -1e30f, m2 = -1e30f, m3 = -1e30f;
#define MSCAN(V) do { const float v_ = (V); \
        const float hi_ = fmaxf(m1, v_), lo_ = fminf(m1, v_); \
        const float hi2_ = fmaxf(m2, lo_), lo2_ = fminf(m2, lo_); \
        m1 = hi_; m2 = hi2_; m3 = fmaxf(m3, lo2_); } while (0)
    MSCAN(lgA[0]); MSCAN(lgA[1]); MSCAN(lgA[2]); MSCAN(lgA[3]);
    MSCAN(lgB[0]); MSCAN(lgB[1]); MSCAN(lgB[2]); MSCAN(lgB[3]);
#undef MSCAN

    int sm = 0;
    sm |= (lgA[0] >= m2) << 0; sm |= (lgA[1] >= m2) << 1;
    sm |= (lgA[2] >= m2) << 2; sm |= (lgA[3] >= m2) << 3;
    sm |= (lgB[0] >= m2) << 4; sm |= (lgB[1] >= m2) << 5;
    sm |= (lgB[2] >= m2) << 6; sm |= (lgB[3] >= m2) << 7;

    if (__any(m2 - m3 < 1e-4f)) {
        f64x4 dA, dB;
        dA[0] = (double)br_lds[0]; dA[1] = (double)br_lds[1];
        dA[2] = (double)br_lds[2]; dA[3] = (double)br_lds[3];
        dB[0] = (double)br_lds[4]; dB[1] = (double)br_lds[5];
        dB[2] = (double)br_lds[6]; dB[3] = (double)br_lds[7];
#define DSTEP(K, XV) do { const double xv_ = (double)(XV); \
        dA = vfmad(xv_, *(const f32x4*)(wr_lds + (K) * NE),     dA); \
        dB = vfmad(xv_, *(const f32x4*)(wr_lds + (K) * NE + 4), dB); } while (0)
        DSTEP(0,  x0[0]); DSTEP(1,  x0[1]); DSTEP(2,  x0[2]); DSTEP(3,  x0[3]);
        DSTEP(4,  x1[0]); DSTEP(5,  x1[1]); DSTEP(6,  x1[2]); DSTEP(7,  x1[3]);
        DSTEP(8,  x2[0]); DSTEP(9,  x2[1]); DSTEP(10, x2[2]); DSTEP(11, x2[3]);
        DSTEP(12, x3[0]); DSTEP(13, x3[1]); DSTEP(14, x3[2]); DSTEP(15, x3[3]);
#undef DSTEP
        double M1 = -1e300, M2 = -1e300;
#define DSCAN(V) do { const double v_ = (V); \
        const double hi_ = fmax(M1, v_); M2 = fmax(M2, fmin(M1, v_)); M1 = hi_; } while (0)
        DSCAN(dA[0]); DSCAN(dA[1]); DSCAN(dA[2]); DSCAN(dA[3]);
        DSCAN(dB[0]); DSCAN(dB[1]); DSCAN(dB[2]); DSCAN(dB[3]);
#undef DSCAN
        sm = 0;
        sm |= (dA[0] >= M2) << 0; sm |= (dA[1] >= M2) << 1;
        sm |= (dA[2] >= M2) << 2; sm |= (dA[3] >= M2) << 3;
        sm |= (dB[0] >= M2) << 4; sm |= (dB[1] >= M2) << 5;
        sm |= (dB[2] >= M2) << 6; sm |= (dB[3] >= M2) << 7;
    }

    const float e0 = __expf(lgA[0] - m1), e1 = __expf(lgA[1] - m1);
    const float e2 = __expf(lgA[2] - m1), e3 = __expf(lgA[3] - m1);
    const float e4 = __expf(lgB[0] - m1), e5 = __expf(lgB[1] - m1);
    const float e6 = __expf(lgB[2] - m1), e7 = __expf(lgB[3] - m1);
    const float inv = 1.0f / (e0 + e1 + e2 + e3 + e4 + e5 + e6 + e7);
    f32x4 gA, gB;
    gA[0] = (sm & 1)   ? e0 * inv : 0.f;  gA[1] = (sm & 2)   ? e1 * inv : 0.f;
    gA[2] = (sm & 4)   ? e2 * inv : 0.f;  gA[3] = (sm & 8)   ? e3 * inv : 0.f;
    gB[0] = (sm & 16)  ? e4 * inv : 0.f;  gB[1] = (sm & 32)  ? e5 * inv : 0.f;
    gB[2] = (sm & 64)  ? e6 * inv : 0.f;  gB[3] = (sm & 128) ? e7 * inv : 0.f;

    f32x4* gp = (f32x4*)(gates + (size_t)t * NE);
    gp[0] = gA;
    gp[1] = gB;
}

// ============================================================================
// Kernel 2: MoE compute. R10 change: process TWO 16-token tiles per expert
// iteration -> a1/a2/b1c/b2c LDS reads amortized over 2 tiles (~halves the
// dominant LDS traffic: 300 KB -> 152 KB per group). Plain stores (nt dropped;
// also A/B-tests the nt write-amplification hypothesis). Live set ~80 regs.
// ============================================================================
__global__ __launch_bounds__(256, 2)
void moe_k(const float* __restrict__ x, const float* __restrict__ gates,
           const float* __restrict__ W1, const float* __restrict__ b1,
           const float* __restrict__ W2, const float* __restrict__ b2,
           float* __restrict__ out, int n_tokens)
{
    __shared__ __align__(16) s16x4 w1lds[NE * 4 * 64];   // 16 KB: [e][n][lane]
    __shared__ __align__(16) s16x4 w2lds[NE * 4 * 64];   // 16 KB: [e][q][lane]
    __shared__ __align__(16) float b1_lds[NE * HID];     // 2 KB
    __shared__ __align__(16) float b2_lds[NE * EMB];     // 512 B
    __shared__ __align__(16) float wt_lds[4 * 8 * TPG];  // 8 KB: [wave][e][tok]

    const int tid = threadIdx.x;

    // ---- per-block: weights fp32->bf16 in per-lane fragment order ----
    // w1lds[(e*4+n)*64 + lane(cg,col)][j] = W1[e][4cg+j][16n+col]   (G1 A-frag, swapped)
    // w2lds[(e*4+q)*64 + lane(cg,col)][j] = W2[e][16q+4cg+j][col]   (G2 A-frag, swapped)
    for (int s = tid; s < NE * 4 * 64; s += 256) {
        const int e = s >> 8, nq = (s >> 6) & 3, l = s & 63;
        const int cc = l & 15, gg = (l >> 4) & 3;
        const float* w1p = W1 + (e * EMB + 4 * gg) * HID + 16 * nq + cc;
        const float* w2p = W2 + (e * HID + 16 * nq + 4 * gg) * EMB + cc;
        w1lds[s] = pack_bf16x4(w1p[0], w1p[HID], w1p[2 * HID], w1p[3 * HID]);
        w2lds[s] = pack_bf16x4(w2p[0], w2p[EMB], w2p[2 * EMB], w2p[3 * EMB]);
    }
    for (int i = tid; i < NE * HID; i += 256) b1_lds[i] = b1[i];
    if (tid < NE * EMB) b2_lds[tid] = b2[tid];
    __syncthreads();

    const int lane = tid & 63;
    const int wid  = tid >> 6;
    const int col  = lane & 15;
    const int cg   = lane >> 4;
    float* wtw = wt_lds + wid * (NE * TPG);   // wave-private gate slab

    const int n_groups = n_tokens / TPG;
    for (int g = blockIdx.x * 4 + wid; g < n_groups; g += gridDim.x * 4) {
        const int tok0 = g * TPG;

        // stage this group's gates: lane loads its token's 8 gates, transposes to [e][tok]
        {
            const f32x4* gp = (const f32x4*)(gates + (size_t)(tok0 + lane) * NE);
            const f32x4 ga = gp[0], gb = gp[1];
#pragma unroll
            for (int e = 0; e < 4; ++e) wtw[e * TPG + lane] = ga[e];
#pragma unroll
            for (int e = 4; e < 8; ++e) wtw[e * TPG + lane] = gb[e - 4];
            // wave-private write->read; compiler orders via lgkmcnt, no barrier
        }

        // ---- two 16-token tiles per pass: weight fragments read once per 2 tiles ----
#pragma unroll 1
        for (int Tp = 0; Tp < 2; ++Tp) {
            const int tokA = tok0 + 32 * Tp + col;        // tile A: tokens 32Tp..32Tp+15
            const int tokB = tokA + 16;                    // tile B: +16

            const f32x4 xvA = *(const f32x4*)(x + (size_t)tokA * EMB + 4 * cg);
            const f32x4 xvB = *(const f32x4*)(x + (size_t)tokB * EMB + 4 * cg);
            const s16x4 xbA = pack_bf16x4(xvA[0], xvA[1], xvA[2], xvA[3]);
            const s16x4 xbB = pack_bf16x4(xvB[0], xvB[1], xvB[2], xvB[3]);

            f32x4 oaccA = {0.f, 0.f, 0.f, 0.f};
            f32x4 oaccB = {0.f, 0.f, 0.f, 0.f};

#pragma unroll 1
            for (int e = 0; e < NE; ++e) {
                const float wvA = wtw[e * TPG + 32 * Tp + col];
                const float wvB = wtw[e * TPG + 32 * Tp + 16 + col];
                // bias term: oacc += w_e * b2[e][4cg+r] (bypasses relu-weighting)
                const f32x4 b2c = *(const f32x4*)(b2_lds + e * EMB + 4 * cg);
                oaccA = vfmaf(wvA, b2c, oaccA);
                oaccB = vfmaf(wvB, b2c, oaccB);

                // G1: h^T tile n (lane: h[tok=col][hid=16n+4cg+r]), C-in = b1.
                // a1/b1c read ONCE, feed both tiles (independent MFMA pairs).
                f32x4 hA[4], hB[4];
#pragma unroll
                for (int n = 0; n < 4; ++n) {
                    const s16x4 a1  = w1lds[(e * 4 + n) * 64 + lane];
                    const f32x4 b1c = *(const f32x4*)(b1_lds + e * HID + 16 * n + 4 * cg);
                    hA[n] = __builtin_amdgcn_mfma_f32_16x16x16bf16_1k(a1, xbA, b1c, 0, 0, 0);
                    hB[n] = __builtin_amdgcn_mfma_f32_16x16x16bf16_1k(a1, xbB, b1c, 0, 0, 0);
                }
                // G2 swapped: eoT[emb][tok]; A = W2^T frag (read once), B = w*relu(h).
                // Two independent C-chains (oaccA/oaccB) interleave in the MFMA pipe.
#pragma unroll
                for (int q = 0; q < 4; ++q) {
                    const s16x4 a2 = w2lds[(e * 4 + q) * 64 + lane];
                    const s16x4 bA = pack_bf16x4(fmaxf(hA[q][0], 0.f) * wvA,
                                                 fmaxf(hA[q][1], 0.f) * wvA,
                                                 fmaxf(hA[q][2], 0.f) * wvA,
                                                 fmaxf(hA[q][3], 0.f) * wvA);
                    const s16x4 bB = pack_bf16x4(fmaxf(hB[q][0], 0.f) * wvB,
                                                 fmaxf(hB[q][1], 0.f) * wvB,
                                                 fmaxf(hB[q][2], 0.f) * wvB,
                                                 fmaxf(hB[q][3], 0.f) * wvB);
                    oaccA = __builtin_amdgcn_mfma_f32_16x16x16bf16_1k(a2, bA, oaccA, 0, 0, 0);
                    oaccB = __builtin_amdgcn_mfma_f32_16x16x16bf16_1k(a2, bB, oaccB, 0, 0, 0);
                }
            }

            // plain stores: one instruction covers 16 full 64-B lines per tile
            *(f32x4*)(out + (size_t)tokA * EMB + 4 * cg) = oaccA;
            *(f32x4*)(out + (size_t)tokB * EMB + 4 * cg) = oaccB;
        }
    }
}

extern "C" void kernel_launch(void* const* d_in, const int* in_sizes, int n_in,
                              void* d_out, int out_size, void* d_ws, size_t ws_size,
                              hipStream_t stream) {
    const float* x  = (const float*)d_in[0];
    const float* Wr = (const float*)d_in[1];
    const float* br = (const float*)d_in[2];
    const float* W1 = (const float*)d_in[3];
    const float* b1 = (const float*)d_in[4];
    const float* W2 = (const float*)d_in[5];
    const float* b2 = (const float*)d_in[6];
    float* out = (float*)d_out;

    const int n_tokens = in_sizes[0] / EMB;   // 262144
    const size_t gates_bytes = (size_t)n_tokens * NE * sizeof(float);  // 8 MB
    float* gates = (float*)d_ws;
    (void)gates_bytes; (void)ws_size;  // harness provides >> 8 MB workspace

    hipLaunchKernelGGL(router_k, dim3((n_tokens + 255) / 256), dim3(256), 0, stream,
                       x, Wr, br, gates, n_tokens);
    hipLaunchKernelGGL(moe_k, dim3(1024), dim3(256), 0, stream,
                       x, gates, W1, b1, W2, b2, out, n_tokens);
}

// Round 11
// 37.070 us; speedup vs baseline: 2.4521x; 1.0636x over previous
//
#include <hip/hip_runtime.h>
#include <hip/hip_bf16.h>

#define EMB 16
#define HID 64
#define NE  8
#define TPG 64   // tokens per wave-group

typedef float  f32x4 __attribute__((ext_vector_type(4)));
typedef double f64x4 __attribute__((ext_vector_type(4)));
typedef short  s16x4 __attribute__((ext_vector_type(4)));

// fp32 -> bf16 via the standard HIP cast (RNE).
__device__ __forceinline__ short f2bf(float f) {
    union { __hip_bfloat16 h; short s; } u;
    u.h = __float2bfloat16(f);
    return u.s;
}
__device__ __forceinline__ s16x4 pack_bf16x4(float a, float b, float c, float d) {
    s16x4 r;
    r[0] = f2bf(a); r[1] = f2bf(b); r[2] = f2bf(c); r[3] = f2bf(d);
    return r;
}

__device__ __forceinline__ f32x4 vfmaf(float s, f32x4 a, f32x4 c) {
    f32x4 r;
    r[0] = fmaf(s, a[0], c[0]); r[1] = fmaf(s, a[1], c[1]);
    r[2] = fmaf(s, a[2], c[2]); r[3] = fmaf(s, a[3], c[3]);
    return r;
}
__device__ __forceinline__ f64x4 vfmad(double s, f32x4 a, f64x4 c) {
    f64x4 r;
    r[0] = fma(s, (double)a[0], c[0]); r[1] = fma(s, (double)a[1], c[1]);
    r[2] = fma(s, (double)a[2], c[2]); r[3] = fma(s, (double)a[3], c[3]);
    return r;
}

// ============================================================================
// Kernel 1: router (byte-identical to round 7 — proven spill-clean).
// One thread per token, ZERO arrays, wave-uniform fp64 rescue.
// ============================================================================
__global__ __launch_bounds__(256, 2)
void router_k(const float* __restrict__ x, const float* __restrict__ Wr,
              const float* __restrict__ br, float* __restrict__ gates,
              int n_tokens)
{
    __shared__ float wr_lds[EMB * NE];
    __shared__ float br_lds[NE];
    const int tid = threadIdx.x;
    if (tid < EMB * NE) wr_lds[tid] = Wr[tid];
    if (tid < NE) br_lds[tid] = br[tid];
    __syncthreads();

    const int t = blockIdx.x * 256 + tid;
    if (t >= n_tokens) return;

    const f32x4* xp = (const f32x4*)(x + (size_t)t * EMB);
    const f32x4 x0 = xp[0], x1 = xp[1], x2 = xp[2], x3 = xp[3];

    f32x4 lgA = *(const f32x4*)(br_lds + 0);
    f32x4 lgB = *(const f32x4*)(br_lds + 4);
#define RSTEP(K, XV) do { const float xv_ = (XV); \
        lgA = vfmaf(xv_, *(const f32x4*)(wr_lds + (K) * NE),     lgA); \
        lgB = vfmaf(xv_, *(const f32x4*)(wr_lds + (K) * NE + 4), lgB); } while (0)
    RSTEP(0,  x0[0]); RSTEP(1,  x0[1]); RSTEP(2,  x0[2]); RSTEP(3,  x0[3]);
    RSTEP(4,  x1[0]); RSTEP(5,  x1[1]); RSTEP(6,  x1[2]); RSTEP(7,  x1[3]);
    RSTEP(8,  x2[0]); RSTEP(9,  x2[1]); RSTEP(10, x2[2]); RSTEP(11, x2[3]);
    RSTEP(12, x3[0]); RSTEP(13, x3[1]); RSTEP(14, x3[2]); RSTEP(15, x3[3]);
#undef RSTEP

    float m1 = -1e30f, m2 = -1e30f, m3 = -1e30f;
#define MSCAN(V) do { const float v_ = (V); \
        const float hi_ = fmaxf(m1, v_), lo_ = fminf(m1, v_); \
        const float hi2_ = fmaxf(m2, lo_), lo2_ = fminf(m2, lo_); \
        m1 = hi_; m2 = hi2_; m3 = fmaxf(m3, lo2_); } while (0)
    MSCAN(lgA[0]); MSCAN(lgA[1]); MSCAN(lgA[2]); MSCAN(lgA[3]);
    MSCAN(lgB[0]); MSCAN(lgB[1]); MSCAN(lgB[2]); MSCAN(lgB[3]);
#undef MSCAN

    int sm = 0;
    sm |= (lgA[0] >= m2) << 0; sm |= (lgA[1] >= m2) << 1;
    sm |= (lgA[2] >= m2) << 2; sm |= (lgA[3] >= m2) << 3;
    sm |= (lgB[0] >= m2) << 4; sm |= (lgB[1] >= m2) << 5;
    sm |= (lgB[2] >= m2) << 6; sm |= (lgB[3] >= m2) << 7;

    if (__any(m2 - m3 < 1e-4f)) {
        f64x4 dA, dB;
        dA[0] = (double)br_lds[0]; dA[1] = (double)br_lds[1];
        dA[2] = (double)br_lds[2]; dA[3] = (double)br_lds[3];
        dB[0] = (double)br_lds[4]; dB[1] = (double)br_lds[5];
        dB[2] = (double)br_lds[6]; dB[3] = (double)br_lds[7];
#define DSTEP(K, XV) do { const double xv_ = (double)(XV); \
        dA = vfmad(xv_, *(const f32x4*)(wr_lds + (K) * NE),     dA); \
        dB = vfmad(xv_, *(const f32x4*)(wr_lds + (K) * NE + 4), dB); } while (0)
        DSTEP(0,  x0[0]); DSTEP(1,  x0[1]); DSTEP(2,  x0[2]); DSTEP(3,  x0[3]);
        DSTEP(4,  x1[0]); DSTEP(5,  x1[1]); DSTEP(6,  x1[2]); DSTEP(7,  x1[3]);
        DSTEP(8,  x2[0]); DSTEP(9,  x2[1]); DSTEP(10, x2[2]); DSTEP(11, x2[3]);
        DSTEP(12, x3[0]); DSTEP(13, x3[1]); DSTEP(14, x3[2]); DSTEP(15, x3[3]);
#undef DSTEP
        double M1 = -1e300, M2 = -1e300;
#define DSCAN(V) do { const double v_ = (V); \
        const double hi_ = fmax(M1, v_); M2 = fmax(M2, fmin(M1, v_)); M1 = hi_; } while (0)
        DSCAN(dA[0]); DSCAN(dA[1]); DSCAN(dA[2]); DSCAN(dA[3]);
        DSCAN(dB[0]); DSCAN(dB[1]); DSCAN(dB[2]); DSCAN(dB[3]);
#undef DSCAN
        sm = 0;
        sm |= (dA[0] >= M2) << 0; sm |= (dA[1] >= M2) << 1;
        sm |= (dA[2] >= M2) << 2; sm |= (dA[3] >= M2) << 3;
        sm |= (dB[0] >= M2) << 4; sm |= (dB[1] >= M2) << 5;
        sm |= (dB[2] >= M2) << 6; sm |= (dB[3] >= M2) << 7;
    }

    const float e0 = __expf(lgA[0] - m1), e1 = __expf(lgA[1] - m1);
    const float e2 = __expf(lgA[2] - m1), e3 = __expf(lgA[3] - m1);
    const float e4 = __expf(lgB[0] - m1), e5 = __expf(lgB[1] - m1);
    const float e6 = __expf(lgB[2] - m1), e7 = __expf(lgB[3] - m1);
    const float inv = 1.0f / (e0 + e1 + e2 + e3 + e4 + e5 + e6 + e7);
    f32x4 gA, gB;
    gA[0] = (sm & 1)   ? e0 * inv : 0.f;  gA[1] = (sm & 2)   ? e1 * inv : 0.f;
    gA[2] = (sm & 4)   ? e2 * inv : 0.f;  gA[3] = (sm & 8)   ? e3 * inv : 0.f;
    gB[0] = (sm & 16)  ? e4 * inv : 0.f;  gB[1] = (sm & 32)  ? e5 * inv : 0.f;
    gB[2] = (sm & 64)  ? e6 * inv : 0.f;  gB[3] = (sm & 128) ? e7 * inv : 0.f;

    f32x4* gp = (f32x4*)(gates + (size_t)t * NE);
    gp[0] = gA;
    gp[1] = gB;
}

// ============================================================================
// Kernel 2: MoE compute. R11 change: per-expert G2 chain.
//   eo_e = chain of 4 MFMAs with C-init = b2 (bias rides the chain free);
//   oacc += wv_e * eo_e  (one FMA merge per expert).
// vs R10's single 32-deep C-chain per tile: critical path 32 MFMA -> 4 MFMA
// (16 independent chains per Tp), and the gate weight costs 4 FMA/e instead
// of 16 v_mul/e in the B-frag prep.
// ============================================================================
__global__ __launch_bounds__(256, 2)
void moe_k(const float* __restrict__ x, const float* __restrict__ gates,
           const float* __restrict__ W1, const float* __restrict__ b1,
           const float* __restrict__ W2, const float* __restrict__ b2,
           float* __restrict__ out, int n_tokens)
{
    __shared__ __align__(16) s16x4 w1lds[NE * 4 * 64];   // 16 KB: [e][n][lane]
    __shared__ __align__(16) s16x4 w2lds[NE * 4 * 64];   // 16 KB: [e][q][lane]
    __shared__ __align__(16) float b1_lds[NE * HID];     // 2 KB
    __shared__ __align__(16) float b2_lds[NE * EMB];     // 512 B
    __shared__ __align__(16) float wt_lds[4 * 8 * TPG];  // 8 KB: [wave][e][tok]

    const int tid = threadIdx.x;

    // ---- per-block: weights fp32->bf16 in per-lane fragment order ----
    // w1lds[(e*4+n)*64 + lane(cg,col)][j] = W1[e][4cg+j][16n+col]   (G1 A-frag, swapped)
    // w2lds[(e*4+q)*64 + lane(cg,col)][j] = W2[e][16q+4cg+j][col]   (G2 A-frag, swapped)
    for (int s = tid; s < NE * 4 * 64; s += 256) {
        const int e = s >> 8, nq = (s >> 6) & 3, l = s & 63;
        const int cc = l & 15, gg = (l >> 4) & 3;
        const float* w1p = W1 + (e * EMB + 4 * gg) * HID + 16 * nq + cc;
        const float* w2p = W2 + (e * HID + 16 * nq + 4 * gg) * EMB + cc;
        w1lds[s] = pack_bf16x4(w1p[0], w1p[HID], w1p[2 * HID], w1p[3 * HID]);
        w2lds[s] = pack_bf16x4(w2p[0], w2p[EMB], w2p[2 * EMB], w2p[3 * EMB]);
    }
    for (int i = tid; i < NE * HID; i += 256) b1_lds[i] = b1[i];
    if (tid < NE * EMB) b2_lds[tid] = b2[tid];
    __syncthreads();

    const int lane = tid & 63;
    const int wid  = tid >> 6;
    const int col  = lane & 15;
    const int cg   = lane >> 4;
    float* wtw = wt_lds + wid * (NE * TPG);   // wave-private gate slab

    const int n_groups = n_tokens / TPG;
    for (int g = blockIdx.x * 4 + wid; g < n_groups; g += gridDim.x * 4) {
        const int tok0 = g * TPG;

        // stage this group's gates: lane loads its token's 8 gates, transposes to [e][tok]
        {
            const f32x4* gp = (const f32x4*)(gates + (size_t)(tok0 + lane) * NE);
            const f32x4 ga = gp[0], gb = gp[1];
#pragma unroll
            for (int e = 0; e < 4; ++e) wtw[e * TPG + lane] = ga[e];
#pragma unroll
            for (int e = 4; e < 8; ++e) wtw[e * TPG + lane] = gb[e - 4];
            // wave-private write->read; compiler orders via lgkmcnt, no barrier
        }

        // ---- two 16-token tiles per pass: weight fragments read once per 2 tiles ----
#pragma unroll 1
        for (int Tp = 0; Tp < 2; ++Tp) {
            const int tokA = tok0 + 32 * Tp + col;        // tile A: tokens 32Tp..32Tp+15
            const int tokB = tokA + 16;                    // tile B: +16

            const f32x4 xvA = *(const f32x4*)(x + (size_t)tokA * EMB + 4 * cg);
            const f32x4 xvB = *(const f32x4*)(x + (size_t)tokB * EMB + 4 * cg);
            const s16x4 xbA = pack_bf16x4(xvA[0], xvA[1], xvA[2], xvA[3]);
            const s16x4 xbB = pack_bf16x4(xvB[0], xvB[1], xvB[2], xvB[3]);

            f32x4 oaccA = {0.f, 0.f, 0.f, 0.f};
            f32x4 oaccB = {0.f, 0.f, 0.f, 0.f};

#pragma unroll 1
            for (int e = 0; e < NE; ++e) {
                const float wvA = wtw[e * TPG + 32 * Tp + col];
                const float wvB = wtw[e * TPG + 32 * Tp + 16 + col];

                // G1: h^T tile n (lane: h[tok=col][hid=16n+4cg+r]), C-in = b1.
                // a1/b1c read ONCE, feed both tiles (8 independent MFMAs).
                f32x4 hA[4], hB[4];
#pragma unroll
                for (int n = 0; n < 4; ++n) {
                    const s16x4 a1  = w1lds[(e * 4 + n) * 64 + lane];
                    const f32x4 b1c = *(const f32x4*)(b1_lds + e * HID + 16 * n + 4 * cg);
                    hA[n] = __builtin_amdgcn_mfma_f32_16x16x16bf16_1k(a1, xbA, b1c, 0, 0, 0);
                    hB[n] = __builtin_amdgcn_mfma_f32_16x16x16bf16_1k(a1, xbB, b1c, 0, 0, 0);
                }

                // G2 swapped: eo_e^T[emb][tok] = W2^T relu(h) + b2, per-expert 4-chain
                // (C-init = b2 -> bias is free on the chain). B-frag = relu only.
                const f32x4 b2c = *(const f32x4*)(b2_lds + e * EMB + 4 * cg);
                f32x4 eoA = b2c, eoB = b2c;
#pragma unroll
                for (int q = 0; q < 4; ++q) {
                    const s16x4 a2 = w2lds[(e * 4 + q) * 64 + lane];
                    const s16x4 bA = pack_bf16x4(fmaxf(hA[q][0], 0.f), fmaxf(hA[q][1], 0.f),
                                                 fmaxf(hA[q][2], 0.f), fmaxf(hA[q][3], 0.f));
                    const s16x4 bB = pack_bf16x4(fmaxf(hB[q][0], 0.f), fmaxf(hB[q][1], 0.f),
                                                 fmaxf(hB[q][2], 0.f), fmaxf(hB[q][3], 0.f));
                    eoA = __builtin_amdgcn_mfma_f32_16x16x16bf16_1k(a2, bA, eoA, 0, 0, 0);
                    eoB = __builtin_amdgcn_mfma_f32_16x16x16bf16_1k(a2, bB, eoB, 0, 0, 0);
                }

                // weighted merge: one FMA per output element per expert
                oaccA = vfmaf(wvA, eoA, oaccA);
                oaccB = vfmaf(wvB, eoB, oaccB);
            }

            // plain stores: wave covers 2 KB contiguous per tile pair
            *(f32x4*)(out + (size_t)tokA * EMB + 4 * cg) = oaccA;
            *(f32x4*)(out + (size_t)tokB * EMB + 4 * cg) = oaccB;
        }
    }
}

extern "C" void kernel_launch(void* const* d_in, const int* in_sizes, int n_in,
                              void* d_out, int out_size, void* d_ws, size_t ws_size,
                              hipStream_t stream) {
    const float* x  = (const float*)d_in[0];
    const float* Wr = (const float*)d_in[1];
    const float* br = (const float*)d_in[2];
    const float* W1 = (const float*)d_in[3];
    const float* b1 = (const float*)d_in[4];
    const float* W2 = (const float*)d_in[5];
    const float* b2 = (const float*)d_in[6];
    float* out = (float*)d_out;

    const int n_tokens = in_sizes[0] / EMB;   // 262144
    float* gates = (float*)d_ws;              // 8 MB of the provided workspace

    hipLaunchKernelGGL(router_k, dim3((n_tokens + 255) / 256), dim3(256), 0, stream,
                       x, Wr, br, gates, n_tokens);
    hipLaunchKernelGGL(moe_k, dim3(1024), dim3(256), 0, stream,
                       x, gates, W1, b1, W2, b2, out, n_tokens);
}